// Round 2
// baseline (4366.382 us; speedup 1.0000x reference)
//
#include <hip/hip_runtime.h>

// MyRnn: 2-layer SimpleRNN, B=1024 T=80 U=1024 E=100.
// Inputs are FLOAT32 (x int32), output FLOAT32. Compute: f16 MFMA, f32 accum.
// Per step t, one kernel computes layer1(t) [z=0] and layer0(t+1) [z=1]
// concurrently (independent given h0_t). 81 sequential GEMM dispatches.

typedef _Float16 h8v __attribute__((ext_vector_type(8)));
typedef float    f4v __attribute__((ext_vector_type(4)));
typedef short    s8v __attribute__((ext_vector_type(8)));

#define UNITS 1024
#define SEQ   80
#define EMBD  100
#define EPAD  128

__device__ __forceinline__ float tanh_fast(float x) {
    x = fminf(15.f, fmaxf(-15.f, x));   // also scrubs NaN
    float e = __expf(2.f * x);
    return (e - 1.f) / (e + 1.f);
}

// embp[r][k] = k<100 ? (f16)emb[r][k] : 0   (10000 x 128)
__global__ void embp_kernel(const float* __restrict__ emb, _Float16* __restrict__ embp) {
    int r = blockIdx.x, k = threadIdx.x;
    embp[r * EPAD + k] = (k < EMBD) ? (_Float16)emb[r * EMBD + k] : (_Float16)0.f;
}

// w0xp[i] = i < 100*1024 ? (f16)w0x[i] : 0   (128 x 1024, row-padded)
__global__ void w0xp_kernel(const float* __restrict__ w, _Float16* __restrict__ wp) {
    int i = blockIdx.x * 256 + threadIdx.x;
    wp[i] = (i < EMBD * UNITS) ? (_Float16)w[i] : (_Float16)0.f;
}

// straight f32 -> f16 convert
__global__ void cvt_kernel(const float* __restrict__ s, _Float16* __restrict__ d) {
    int i = blockIdx.x * 256 + threadIdx.x;
    d[i] = (_Float16)s[i];
}

__global__ void zero_kernel(s8v* __restrict__ p) {
    p[blockIdx.x * 256 + threadIdx.x] = (s8v)0;
}

struct GemmTask {
    const _Float16* A0; const _Float16* B0;
    const int* xidx;                  // if set: A0 row b = A0 + xidx[b*SEQ]*EPAD
    int K0; int lda0;
    const _Float16* A1; const _Float16* B1;   // K=1024, lda=1024
    const float* bias; _Float16* out;
};

// out[b][u] = tanh( A0@B0 + A1@B1 + bias ); 64x64 tile, 4 waves (2x2 of 32x32)
__launch_bounds__(256)
__global__ void step_kernel(GemmTask Ta, GemmTask Tb) {
    GemmTask T = (blockIdx.z == 0) ? Ta : Tb;
    __shared__ _Float16 As[64 * 40];   // A tile [64 m][32 k], stride 40
    __shared__ _Float16 Bt[64 * 40];   // B tile transposed [64 n][32 k], stride 40

    int tid  = threadIdx.x;
    int lane = tid & 63, wid = tid >> 6;
    int wm = wid >> 1, wn = wid & 1;
    int quad = lane >> 4, l16 = lane & 15;
    int row0 = blockIdx.y * 64, col0 = blockIdx.x * 64;

    f4v acc[2][2] = {};

    int ar = tid >> 2, ac = (tid & 3) * 8;   // A stage: 64 rows x 4 chunks of 8
    int br = tid >> 3, bc = (tid & 7) * 8;   // B stage: 32 k-rows x 8 chunks of 8

    const _Float16* a0row = T.xidx
        ? T.A0 + (size_t)T.xidx[(row0 + ar) * SEQ] * EPAD
        : T.A0 + (size_t)(row0 + ar) * T.lda0;
    const _Float16* a1row = T.A1 + (size_t)(row0 + ar) * UNITS;

    for (int s = 0; s < 2; ++s) {
        const _Float16* arow = s ? a1row : a0row;
        const _Float16* B    = s ? T.B1  : T.B0;
        int K = s ? UNITS : T.K0;
        for (int k0 = 0; k0 < K; k0 += 32) {
            h8v av = *(const h8v*)(arow + k0 + ac);
            h8v bv = *(const h8v*)(B + (size_t)(k0 + br) * UNITS + col0 + bc);
            *(h8v*)(As + ar * 40 + ac) = av;
            #pragma unroll
            for (int j = 0; j < 8; ++j) Bt[(bc + j) * 40 + br] = bv[j];
            __syncthreads();
            #pragma unroll
            for (int i = 0; i < 2; ++i) {
                h8v af = *(const h8v*)(As + (wm * 32 + i * 16 + l16) * 40 + quad * 8);
                #pragma unroll
                for (int j = 0; j < 2; ++j) {
                    h8v bf = *(const h8v*)(Bt + (wn * 32 + j * 16 + l16) * 40 + quad * 8);
                    acc[i][j] = __builtin_amdgcn_mfma_f32_16x16x32_f16(af, bf, acc[i][j], 0, 0, 0);
                }
            }
            __syncthreads();
        }
    }

    #pragma unroll
    for (int i = 0; i < 2; ++i) {
        int r = row0 + wm * 32 + i * 16 + quad * 4;
        #pragma unroll
        for (int j = 0; j < 2; ++j) {
            int c = col0 + wn * 32 + j * 16 + l16;
            float bias = T.bias[c];
            #pragma unroll
            for (int g = 0; g < 4; ++g) {
                float v = tanh_fast(acc[i][j][g] + bias);
                T.out[(size_t)(r + g) * UNITS + c] = (_Float16)v;
            }
        }
    }
}

// out[b] = sigmoid( h1[b]·Wout + bout ), one wave per row
__global__ void out_kernel(const _Float16* __restrict__ h1, const float* __restrict__ wout,
                           const float* __restrict__ bout, float* __restrict__ out) {
    int row  = blockIdx.x * 4 + (threadIdx.x >> 6);
    int lane = threadIdx.x & 63;
    const _Float16* hr = h1 + (size_t)row * UNITS;
    float sacc = 0.f;
    #pragma unroll
    for (int i = 0; i < 16; ++i)
        sacc += (float)hr[i * 64 + lane] * wout[i * 64 + lane];
    #pragma unroll
    for (int off = 32; off; off >>= 1) sacc += __shfl_down(sacc, off);
    if (lane == 0) {
        float z = sacc + bout[0];
        out[row] = 1.f / (1.f + __expf(-z));
    }
}

extern "C" void kernel_launch(void* const* d_in, const int* in_sizes, int n_in,
                              void* d_out, int out_size, void* d_ws, size_t ws_size,
                              hipStream_t stream) {
    const int*   x    = (const int*)d_in[0];
    const float* emb  = (const float*)d_in[1];
    const float* W0x  = (const float*)d_in[2];
    const float* W0h  = (const float*)d_in[3];
    const float* b0   = (const float*)d_in[4];
    const float* W1x  = (const float*)d_in[5];
    const float* W1h  = (const float*)d_in[6];
    const float* b1   = (const float*)d_in[7];
    const float* Wout = (const float*)d_in[8];
    const float* bout = (const float*)d_in[9];
    float* out = (float*)d_out;

    char* ws = (char*)d_ws;
    _Float16* EMBP  = (_Float16*)ws;                         // 10000*128*2 = 2,560,000 B
    _Float16* W0XP  = (_Float16*)(ws + 2560000);             // 128*1024*2  =   262,144 B
    _Float16* W0H16 = (_Float16*)(ws + 2560000 + 262144);
    _Float16* W1X16 = W0H16 + 1024 * 1024;
    _Float16* W1H16 = W1X16 + 1024 * 1024;
    _Float16* Hbuf  = W1H16 + 1024 * 1024;                   // 4 x 2 MB
    _Float16* H0[2] = { Hbuf,                   Hbuf + 1024 * 1024 };
    _Float16* H1[2] = { Hbuf + 2 * 1024 * 1024, Hbuf + 3 * 1024 * 1024 };

    embp_kernel<<<10000, EPAD, 0, stream>>>(emb, EMBP);
    w0xp_kernel<<<512, 256, 0, stream>>>(W0x, W0XP);
    cvt_kernel<<<4096, 256, 0, stream>>>(W0h, W0H16);
    cvt_kernel<<<4096, 256, 0, stream>>>(W1x, W1X16);
    cvt_kernel<<<4096, 256, 0, stream>>>(W1h, W1H16);
    zero_kernel<<<2048, 256, 0, stream>>>((s8v*)Hbuf);       // zero all 4 H buffers (8 MB)

    // prologue: h0_0 = tanh(emb[x[:,0]] @ W0xp + 0 @ W0h + b0) -> H0[0]
    GemmTask p;
    p.A0 = EMBP; p.B0 = W0XP; p.xidx = x; p.K0 = EPAD; p.lda0 = EPAD;
    p.A1 = H0[1]; p.B1 = W0H16; p.bias = b0; p.out = H0[0];
    step_kernel<<<dim3(16, 16, 1), 256, 0, stream>>>(p, p);

    for (int t = 0; t < SEQ; ++t) {
        // z=0: h1_t = tanh(h0_t @ W1x + h1_{t-1} @ W1h + b1) -> H1[t&1]
        GemmTask l1;
        l1.A0 = H0[t & 1]; l1.B0 = W1X16; l1.xidx = nullptr; l1.K0 = UNITS; l1.lda0 = UNITS;
        l1.A1 = H1[(t + 1) & 1]; l1.B1 = W1H16; l1.bias = b1; l1.out = H1[t & 1];
        if (t < SEQ - 1) {
            // z=1: h0_{t+1} = tanh(emb[x[:,t+1]] @ W0xp + h0_t @ W0h + b0) -> H0[(t+1)&1]
            GemmTask l0;
            l0.A0 = EMBP; l0.B0 = W0XP; l0.xidx = x + (t + 1); l0.K0 = EPAD; l0.lda0 = EPAD;
            l0.A1 = H0[t & 1]; l0.B1 = W0H16; l0.bias = b0; l0.out = H0[(t + 1) & 1];
            step_kernel<<<dim3(16, 16, 2), 256, 0, stream>>>(l1, l0);
        } else {
            step_kernel<<<dim3(16, 16, 1), 256, 0, stream>>>(l1, l1);
        }
    }

    out_kernel<<<256, 256, 0, stream>>>(H1[1], Wout, bout, out);
}

// Round 3
// 1580.033 us; speedup vs baseline: 2.7635x; 2.7635x over previous
//
#include <hip/hip_runtime.h>

// MyRnn: 2-layer SimpleRNN, B=1024 T=80 U=1024 E=100. f32 I/O, f16 MFMA compute.
// v3: weights pre-transposed to [N][K] once per call; step GEMM uses
// global_load_lds dwordx4 staging with XOR-8 swizzle (conflict-free ds_read_b128),
// KC=128, 64x64 tile, 512 blocks (2/CU co-resident).

typedef _Float16 h8v __attribute__((ext_vector_type(8)));
typedef float    f4v __attribute__((ext_vector_type(4)));
typedef short    s8v __attribute__((ext_vector_type(8)));

#define UNITS 1024
#define SEQ   80
#define EMBD  100
#define EPAD  128
#define KC    128

__device__ __forceinline__ float tanh_fast(float x) {
    x = fminf(15.f, fmaxf(-15.f, x));   // also scrubs NaN
    float e = __expf(2.f * x);
    return (e - 1.f) / (e + 1.f);
}

__device__ __forceinline__ void gl_lds16(const _Float16* g, _Float16* l) {
    __builtin_amdgcn_global_load_lds(
        (const __attribute__((address_space(1))) void*)g,
        (__attribute__((address_space(3))) void*)l, 16, 0, 0);
}

// embp[r][k] = k<100 ? (f16)emb[r][k] : 0   (10000 x 128)
__global__ void embp_kernel(const float* __restrict__ emb, _Float16* __restrict__ embp) {
    int r = blockIdx.x, k = threadIdx.x;
    embp[r * EPAD + k] = (k < EMBD) ? (_Float16)emb[r * EMBD + k] : (_Float16)0.f;
}

// wt[n][kp] = kp<K ? (f16)w[kp][n] : 0 ; wt row stride Kpad. block (32,8).
__global__ void tpad_kernel(const float* __restrict__ w, _Float16* __restrict__ wt,
                            int K, int Kpad, int N) {
    __shared__ float t[32][33];
    int k0 = blockIdx.x * 32, n0 = blockIdx.y * 32;
    int tx = threadIdx.x, ty = threadIdx.y;
    for (int i = ty; i < 32; i += 8) {
        int k = k0 + i;
        t[i][tx] = (k < K) ? w[(size_t)k * N + n0 + tx] : 0.f;
    }
    __syncthreads();
    for (int i = ty; i < 32; i += 8)
        wt[(size_t)(n0 + i) * Kpad + k0 + tx] = (_Float16)t[tx][i];
}

__global__ void zero_kernel(s8v* __restrict__ p) {
    p[blockIdx.x * 256 + threadIdx.x] = (s8v)0;
}

struct GemmTask {
    const _Float16* A0;      // row-major [.][lda0] (or gather base if xidx)
    const _Float16* B0T;     // [1024 n][ldb0 k]
    const int* xidx;         // if set: A0 row b = A0 + xidx[b*SEQ]*EPAD
    int nch0, lda0, ldb0;    // nch0 = K0/KC chunks for source 0
    const _Float16* A1;      // [1024][1024]
    const _Float16* B1T;     // [1024][1024]
    const float* bias; _Float16* out;
};

// out[b][u] = tanh( A0@B0 + A1@B1 + bias ); 64x64 tile, 4 waves (2x2 of 32x32)
__launch_bounds__(256)
__global__ void step_kernel(GemmTask Ta, GemmTask Tb) {
    GemmTask T = (blockIdx.z == 0) ? Ta : Tb;
    __shared__ _Float16 As[64 * KC];   // 16 KB, row stride 128 halves, XOR-8 swizzle
    __shared__ _Float16 Bs[64 * KC];   // 16 KB

    int tid  = threadIdx.x;
    int lane = tid & 63, w = tid >> 6;
    int wm = w >> 1, wn = w & 1;
    int quad = lane >> 4, l16 = lane & 15;
    int row0 = blockIdx.y * 64, col0 = blockIdx.x * 64;

    f4v acc[2][2] = {};

    // staging geometry: wave-instr g = w*4+q covers rows [g*4, g*4+4), lane l ->
    // row r = g*4 + (l>>4), stored unit u' = l&15, logical unit u = u' ^ (r&7)
    int rr[4]; int goff[4];
    const _Float16* a0p[4]; const _Float16* a1p[4];
    const _Float16* b0p[4]; const _Float16* b1p[4];
    #pragma unroll
    for (int q = 0; q < 4; ++q) {
        int g = w * 4 + q;
        int r = g * 4 + (lane >> 4);
        rr[q] = g * 512;                          // LDS base (halves) for this wave-instr
        goff[q] = 8 * ((lane & 15) ^ (r & 7));    // swizzled k-offset (halves)
        a0p[q] = T.xidx ? T.A0 + (size_t)T.xidx[(size_t)(row0 + r) * SEQ] * EPAD
                        : T.A0 + (size_t)(row0 + r) * T.lda0;
        a1p[q] = T.A1 + (size_t)(row0 + r) * UNITS;
        b0p[q] = T.B0T + (size_t)(col0 + r) * T.ldb0;
        b1p[q] = T.B1T + (size_t)(col0 + r) * UNITS;
    }

    for (int s = 0; s < 2; ++s) {
        int nch = s ? (UNITS / KC) : T.nch0;
        for (int c = 0; c < nch; ++c) {
            int k0 = c * KC;
            #pragma unroll
            for (int q = 0; q < 4; ++q) {
                const _Float16* ap = (s ? a1p[q] : a0p[q]) + k0 + goff[q];
                const _Float16* bp = (s ? b1p[q] : b0p[q]) + k0 + goff[q];
                gl_lds16(ap, As + rr[q]);
                gl_lds16(bp, Bs + rr[q]);
            }
            __syncthreads();   // drains vmcnt (global_load_lds) before reads
            #pragma unroll
            for (int kk = 0; kk < 4; ++kk) {
                int us = 8 * ((kk * 4 + quad) ^ (l16 & 7));
                h8v af[2], bf[2];
                #pragma unroll
                for (int i = 0; i < 2; ++i)
                    af[i] = *(const h8v*)(As + (wm * 32 + i * 16 + l16) * KC + us);
                #pragma unroll
                for (int j = 0; j < 2; ++j)
                    bf[j] = *(const h8v*)(Bs + (wn * 32 + j * 16 + l16) * KC + us);
                #pragma unroll
                for (int i = 0; i < 2; ++i)
                    #pragma unroll
                    for (int j = 0; j < 2; ++j)
                        acc[i][j] = __builtin_amdgcn_mfma_f32_16x16x32_f16(
                            af[i], bf[j], acc[i][j], 0, 0, 0);
            }
            __syncthreads();   // protect LDS before next stage
        }
    }

    #pragma unroll
    for (int i = 0; i < 2; ++i) {
        int r = row0 + wm * 32 + i * 16 + quad * 4;
        #pragma unroll
        for (int j = 0; j < 2; ++j) {
            int c = col0 + wn * 32 + j * 16 + l16;
            float bias = T.bias[c];
            #pragma unroll
            for (int g = 0; g < 4; ++g) {
                float v = tanh_fast(acc[i][j][g] + bias);
                T.out[(size_t)(r + g) * UNITS + c] = (_Float16)v;
            }
        }
    }
}

// out[b] = sigmoid( h1[b]·Wout + bout ), one wave per row
__global__ void out_kernel(const _Float16* __restrict__ h1, const float* __restrict__ wout,
                           const float* __restrict__ bout, float* __restrict__ out) {
    int row  = blockIdx.x * 4 + (threadIdx.x >> 6);
    int lane = threadIdx.x & 63;
    const _Float16* hr = h1 + (size_t)row * UNITS;
    float sacc = 0.f;
    #pragma unroll
    for (int i = 0; i < 16; ++i)
        sacc += (float)hr[i * 64 + lane] * wout[i * 64 + lane];
    #pragma unroll
    for (int off = 32; off; off >>= 1) sacc += __shfl_down(sacc, off);
    if (lane == 0) {
        float z = sacc + bout[0];
        out[row] = 1.f / (1.f + __expf(-z));
    }
}

extern "C" void kernel_launch(void* const* d_in, const int* in_sizes, int n_in,
                              void* d_out, int out_size, void* d_ws, size_t ws_size,
                              hipStream_t stream) {
    const int*   x    = (const int*)d_in[0];
    const float* emb  = (const float*)d_in[1];
    const float* W0x  = (const float*)d_in[2];
    const float* W0h  = (const float*)d_in[3];
    const float* b0   = (const float*)d_in[4];
    const float* W1x  = (const float*)d_in[5];
    const float* W1h  = (const float*)d_in[6];
    const float* b1   = (const float*)d_in[7];
    const float* Wout = (const float*)d_in[8];
    const float* bout = (const float*)d_in[9];
    float* out = (float*)d_out;

    char* ws = (char*)d_ws;
    _Float16* EMBP = (_Float16*)ws;                          // 10000*128*2 = 2,560,000 B
    _Float16* W0XT = (_Float16*)(ws + 2560000);              // [1024][128]  = 262,144 B
    _Float16* W0HT = W0XT + 1024 * EPAD;                     // [1024][1024] x3
    _Float16* W1XT = W0HT + 1024 * 1024;
    _Float16* W1HT = W1XT + 1024 * 1024;
    _Float16* Hbuf = W1HT + 1024 * 1024;                     // 4 x 2 MB
    _Float16* H0[2] = { Hbuf,                   Hbuf + 1024 * 1024 };
    _Float16* H1[2] = { Hbuf + 2 * 1024 * 1024, Hbuf + 3 * 1024 * 1024 };

    embp_kernel<<<10000, EPAD, 0, stream>>>(emb, EMBP);
    tpad_kernel<<<dim3(4, 32),  dim3(32, 8), 0, stream>>>(W0x, W0XT, EMBD, EPAD, UNITS);
    tpad_kernel<<<dim3(32, 32), dim3(32, 8), 0, stream>>>(W0h, W0HT, UNITS, UNITS, UNITS);
    tpad_kernel<<<dim3(32, 32), dim3(32, 8), 0, stream>>>(W1x, W1XT, UNITS, UNITS, UNITS);
    tpad_kernel<<<dim3(32, 32), dim3(32, 8), 0, stream>>>(W1h, W1HT, UNITS, UNITS, UNITS);
    zero_kernel<<<2048, 256, 0, stream>>>((s8v*)Hbuf);       // zero all 4 H buffers (8 MB)

    // prologue: h0_0 = tanh(emb[x[:,0]] @ W0x + 0 @ W0h + b0) -> H0[0]
    GemmTask p;
    p.A0 = EMBP; p.B0T = W0XT; p.xidx = x; p.nch0 = 1; p.lda0 = EPAD; p.ldb0 = EPAD;
    p.A1 = H0[1]; p.B1T = W0HT; p.bias = b0; p.out = H0[0];
    step_kernel<<<dim3(16, 16, 1), 256, 0, stream>>>(p, p);

    for (int t = 0; t < SEQ; ++t) {
        // z=0: h1_t = tanh(h0_t @ W1x + h1_{t-1} @ W1h + b1) -> H1[t&1]
        GemmTask l1;
        l1.A0 = H0[t & 1]; l1.B0T = W1XT; l1.xidx = nullptr;
        l1.nch0 = UNITS / KC; l1.lda0 = UNITS; l1.ldb0 = UNITS;
        l1.A1 = H1[(t + 1) & 1]; l1.B1T = W1HT; l1.bias = b1; l1.out = H1[t & 1];
        if (t < SEQ - 1) {
            // z=1: h0_{t+1} = tanh(emb[x[:,t+1]] @ W0x + h0_t @ W0h + b0) -> H0[(t+1)&1]
            GemmTask l0;
            l0.A0 = EMBP; l0.B0T = W0XT; l0.xidx = x + (t + 1);
            l0.nch0 = 1; l0.lda0 = EPAD; l0.ldb0 = EPAD;
            l0.A1 = H0[t & 1]; l0.B1T = W0HT; l0.bias = b0; l0.out = H0[(t + 1) & 1];
            step_kernel<<<dim3(16, 16, 2), 256, 0, stream>>>(l1, l0);
        } else {
            step_kernel<<<dim3(16, 16, 1), 256, 0, stream>>>(l1, l1);
        }
    }

    out_kernel<<<256, 256, 0, stream>>>(H1[1], Wout, bout, out);
}